// Round 4
// baseline (623.179 us; speedup 1.0000x reference)
//
#include <hip/hip_runtime.h>
#include <math.h>

// N=50000, E=1600000, F_IN=128, C_OUT=64, HEADS=2, HC=128
#define NEG_SLOPE 0.2f
#define GN_EPS 1e-5f
#define BSHIFT 4  // 16 nodes per bucket

// ---------------------------------------------------------------------------
// K1: xl = x @ W_l, xr = x @ W_r.  Block = 256 thr, tile 32 rows x 256 cols.
// ---------------------------------------------------------------------------
__global__ __launch_bounds__(256) void gemm_xw(
    const float* __restrict__ x, const float* __restrict__ Wl,
    const float* __restrict__ Wr, float* __restrict__ xl,
    float* __restrict__ xr, int n) {
  __shared__ float xs[32][128];
  const int tid = threadIdx.x;
  const int r0 = blockIdx.x * 32;
  const int rows = min(32, n - r0);

#pragma unroll
  for (int j = 0; j < 4; ++j) {
    int f4 = j * 256 + tid;
    int row = f4 >> 5;
    int c4 = f4 & 31;
    float4 v = make_float4(0.f, 0.f, 0.f, 0.f);
    if (row < rows) v = ((const float4*)(x + (size_t)(r0 + row) * 128))[c4];
    ((float4*)&xs[row][0])[c4] = v;
  }
  __syncthreads();

  const int rg = tid >> 6;
  const int cg = tid & 63;
  const float* __restrict__ W = (cg < 32) ? Wl : Wr;
  const int cb = (cg < 32) ? 4 * cg : 4 * cg - 128;

  float4 acc[8];
#pragma unroll
  for (int r = 0; r < 8; ++r) acc[r] = make_float4(0.f, 0.f, 0.f, 0.f);

#pragma unroll 4
  for (int k4 = 0; k4 < 32; ++k4) {
    float4 xv[8];
#pragma unroll
    for (int r = 0; r < 8; ++r)
      xv[r] = *(const float4*)&xs[rg * 8 + r][k4 * 4];
    float4 w0 = *(const float4*)(W + (size_t)(4 * k4 + 0) * 128 + cb);
    float4 w1 = *(const float4*)(W + (size_t)(4 * k4 + 1) * 128 + cb);
    float4 w2 = *(const float4*)(W + (size_t)(4 * k4 + 2) * 128 + cb);
    float4 w3 = *(const float4*)(W + (size_t)(4 * k4 + 3) * 128 + cb);
#pragma unroll
    for (int r = 0; r < 8; ++r) {
      acc[r].x = fmaf(xv[r].x, w0.x, acc[r].x);
      acc[r].y = fmaf(xv[r].x, w0.y, acc[r].y);
      acc[r].z = fmaf(xv[r].x, w0.z, acc[r].z);
      acc[r].w = fmaf(xv[r].x, w0.w, acc[r].w);
      acc[r].x = fmaf(xv[r].y, w1.x, acc[r].x);
      acc[r].y = fmaf(xv[r].y, w1.y, acc[r].y);
      acc[r].z = fmaf(xv[r].y, w1.z, acc[r].z);
      acc[r].w = fmaf(xv[r].y, w1.w, acc[r].w);
      acc[r].x = fmaf(xv[r].z, w2.x, acc[r].x);
      acc[r].y = fmaf(xv[r].z, w2.y, acc[r].y);
      acc[r].z = fmaf(xv[r].z, w2.z, acc[r].z);
      acc[r].w = fmaf(xv[r].z, w2.w, acc[r].w);
      acc[r].x = fmaf(xv[r].w, w3.x, acc[r].x);
      acc[r].y = fmaf(xv[r].w, w3.y, acc[r].y);
      acc[r].z = fmaf(xv[r].w, w3.z, acc[r].z);
      acc[r].w = fmaf(xv[r].w, w3.w, acc[r].w);
    }
  }

  float* __restrict__ dst = (cg < 32) ? xl : xr;
#pragma unroll
  for (int r = 0; r < 8; ++r) {
    int row = rg * 8 + r;
    if (row < rows)
      *(float4*)(dst + (size_t)(r0 + row) * 128 + cb) = acc[r];
  }
}

// ---------------------------------------------------------------------------
// K2: in-degree histogram (dst = ei[e..2e))
// ---------------------------------------------------------------------------
__global__ void hist_kernel(const int* __restrict__ ei, int* __restrict__ count,
                            int e) {
  int i = blockIdx.x * blockDim.x + threadIdx.x;
  if (i < e) atomicAdd(&count[ei[e + i]], 1);
}

// K3a: per-chunk (256 counts) sums
__global__ __launch_bounds__(256) void scan_chunks(const int* __restrict__ count,
                                                   int* __restrict__ chunkSum,
                                                   int n) {
  __shared__ int sd[256];
  int i = blockIdx.x * 256 + threadIdx.x;
  sd[threadIdx.x] = (i < n) ? count[i] : 0;
  __syncthreads();
#pragma unroll
  for (int s = 128; s > 0; s >>= 1) {
    if (threadIdx.x < s) sd[threadIdx.x] += sd[threadIdx.x + s];
    __syncthreads();
  }
  if (threadIdx.x == 0) chunkSum[blockIdx.x] = sd[0];
}

// K3b: parallel exclusive scan of chunk sums (nchunk <= 256), one block
__global__ __launch_bounds__(256) void scan_top(const int* __restrict__ chunkSum,
                                                int* __restrict__ chunkOff,
                                                int nchunk) {
  __shared__ int sd[256];
  int t = threadIdx.x;
  int v = (t < nchunk) ? chunkSum[t] : 0;
  sd[t] = v;
  __syncthreads();
#pragma unroll
  for (int s = 1; s < 256; s <<= 1) {
    int add = (t >= s) ? sd[t - s] : 0;
    __syncthreads();
    sd[t] += add;
    __syncthreads();
  }
  if (t < nchunk) chunkOff[t] = sd[t] - v;
}

// K3c: per-chunk parallel exclusive scan -> offsets + cursor
__global__ __launch_bounds__(256) void scan_fill(
    const int* __restrict__ count, const int* __restrict__ chunkOff,
    int* __restrict__ offsets, int* __restrict__ cursor, int n, int e) {
  __shared__ int sd[256];
  int b = blockIdx.x, t = threadIdx.x;
  int i = b * 256 + t;
  int v = (i < n) ? count[i] : 0;
  sd[t] = v;
  __syncthreads();
#pragma unroll
  for (int s = 1; s < 256; s <<= 1) {
    int add = (t >= s) ? sd[t - s] : 0;
    __syncthreads();
    sd[t] += add;
    __syncthreads();
  }
  if (i < n) {
    int off = chunkOff[b] + sd[t] - v;
    offsets[i] = off;
    cursor[i] = off;
  }
  if (i == 0) offsets[n] = e;
}

// K4a: init bucket cursors from node offsets (bucket b starts at node b*16)
__global__ void init_bcur(const int* __restrict__ offsets,
                          int* __restrict__ bcur, int nb, int n) {
  int b = blockIdx.x * blockDim.x + threadIdx.x;
  if (b < nb) bcur[b] = offsets[min(b << BSHIFT, n)];
}

// K4b: radix-partition edges into dst-buckets of 16 nodes.
// Packed entry: src (16 bits, n<65536) | (dst&15) << 16. Writes land in
// ~2KB per-bucket windows -> L2 lines fill before eviction (vs the 101MB
// partial-line writeback thrash of the flat scatter, R3 counters).
__global__ void bucketize(const int* __restrict__ ei, int* __restrict__ bcur,
                          unsigned int* __restrict__ ebuf, int e) {
  int i = blockIdx.x * blockDim.x + threadIdx.x;
  if (i < e) {
    int dst = ei[e + i];
    int src = ei[i];
    int b = dst >> BSHIFT;
    int pos = atomicAdd(&bcur[b], 1);
    ebuf[pos] = (unsigned int)src | ((unsigned int)(dst & 15) << 16);
  }
}

// K4c: per-bucket CSR scatter. One block per bucket; cursor atomics and
// csr writes confined to the bucket's ~2KB window.
__global__ __launch_bounds__(256) void bucket_scatter(
    const unsigned int* __restrict__ ebuf, const int* __restrict__ offsets,
    int* __restrict__ cursor, int* __restrict__ csr_src, int n) {
  const int b = blockIdx.x;
  const int node0 = b << BSHIFT;
  const int seg0 = offsets[node0];
  const int seg1 = offsets[min(node0 + 16, n)];
  for (int i = seg0 + threadIdx.x; i < seg1; i += 256) {
    unsigned int v = ebuf[i];
    int src = (int)(v & 0xFFFFu);
    int dst = node0 | (int)(v >> 16);
    int pos = atomicAdd(&cursor[dst], 1);
    csr_src[pos] = src;
  }
}

// ---------------------------------------------------------------------------
// K5: per-node softmax attention + aggregation.
// One wave per node. Lane l owns channel pair (2l, 2l+1): lanes 0..31 =
// head0, lanes 32..63 = head1. One float2 gather per edge; one 5-level
// butterfly reduces both heads at once. No max subtraction (validated R2/R3).
// ---------------------------------------------------------------------------
__global__ __launch_bounds__(256) void node_agg(
    const float* __restrict__ xl, const float* __restrict__ xr,
    const int* __restrict__ offsets, const int* __restrict__ csr_src,
    const float* __restrict__ att, const float* __restrict__ bias,
    float* __restrict__ out, int n) {
  const int wave = threadIdx.x >> 6;
  const int lane = threadIdx.x & 63;
  const int node = blockIdx.x * 4 + wave;
  if (node >= n) return;
  const int ch = lane * 2;

  const float2 xr2 = *(const float2*)(xr + (size_t)node * 128 + ch);
  const float2 a2 = *(const float2*)(att + ch);

  const int start = offsets[node];
  const int end = offsets[node + 1];

  float s = 0.f;
  float2 acc = make_float2(0.f, 0.f);

  auto edge_body = [&](float2 v) {
    float t0 = v.x + xr2.x;
    float t1 = v.y + xr2.y;
    t0 = fmaxf(t0, 0.f) + NEG_SLOPE * fminf(t0, 0.f);
    t1 = fmaxf(t1, 0.f) + NEG_SLOPE * fminf(t1, 0.f);
    float p = fmaf(t0, a2.x, t1 * a2.y);
    p += __shfl_xor(p, 1, 64);
    p += __shfl_xor(p, 2, 64);
    p += __shfl_xor(p, 4, 64);
    p += __shfl_xor(p, 8, 64);
    p += __shfl_xor(p, 16, 64);
    float w = __expf(p);
    s += w;
    acc.x = fmaf(w, v.x, acc.x);
    acc.y = fmaf(w, v.y, acc.y);
  };

  edge_body(*(const float2*)(xl + (size_t)node * 128 + ch));

  int e = start;
  for (; e + 1 < end; e += 2) {
    int src0 = csr_src[e];
    int src1 = csr_src[e + 1];
    float2 va = *(const float2*)(xl + (size_t)src0 * 128 + ch);
    float2 vb = *(const float2*)(xl + (size_t)src1 * 128 + ch);
    edge_body(va);
    edge_body(vb);
  }
  if (e < end) {
    int src0 = csr_src[e];
    edge_body(*(const float2*)(xl + (size_t)src0 * 128 + ch));
  }

  const float inv = 1.f / s;
  const float2 b2 = *(const float2*)(bias + ch);
  float2 o = make_float2(fmaf(acc.x, inv, b2.x), fmaf(acc.y, inv, b2.y));
  *(float2*)(out + (size_t)node * 128 + ch) = o;
}

// ---------------------------------------------------------------------------
// K6a: per-channel sum & sumsq partials
// ---------------------------------------------------------------------------
__global__ __launch_bounds__(256) void gn_partial(const float* __restrict__ out,
                                                  float* __restrict__ part,
                                                  int total) {
  float s = 0.f, q = 0.f;
  const int stride = gridDim.x * 256;
  for (int idx = blockIdx.x * 256 + threadIdx.x; idx < total; idx += stride) {
    float v = out[idx];
    s += v;
    q = fmaf(v, v, q);
  }
  __shared__ float sd[256], qd[256];
  sd[threadIdx.x] = s;
  qd[threadIdx.x] = q;
  __syncthreads();
  if (threadIdx.x < 128) {
    part[blockIdx.x * 256 + threadIdx.x] = sd[threadIdx.x] + sd[threadIdx.x + 128];
    part[blockIdx.x * 256 + 128 + threadIdx.x] =
        qd[threadIdx.x] + qd[threadIdx.x + 128];
  }
}

// K6b: combine partials, produce affine params A,B
__global__ void gn_final(const float* __restrict__ part,
                         const float* __restrict__ gw,
                         const float* __restrict__ gb,
                         const float* __restrict__ gms, float* __restrict__ AB,
                         int nblocks, float inv_n) {
  int c = threadIdx.x;  // 128 threads
  float S = 0.f, Q = 0.f;
  for (int b = 0; b < nblocks; ++b) {
    S += part[b * 256 + c];
    Q += part[b * 256 + 128 + c];
  }
  float mean = S * inv_n;
  float msc = mean * gms[c];
  float var = Q * inv_n - 2.f * msc * mean + msc * msc;
  float scale = gw[c] * rsqrtf(var + GN_EPS);
  AB[c] = scale;
  AB[128 + c] = gb[c] - scale * msc;
}

// K7: in-place normalize, float4-vectorized
__global__ void gn_apply(float* __restrict__ out, const float* __restrict__ AB,
                         int total4) {
  int i = blockIdx.x * blockDim.x + threadIdx.x;
  if (i >= total4) return;
  float4 v = ((float4*)out)[i];
  int c4 = (i & 31) * 4;
  v.x = fmaf(AB[c4 + 0], v.x, AB[128 + c4 + 0]);
  v.y = fmaf(AB[c4 + 1], v.y, AB[128 + c4 + 1]);
  v.z = fmaf(AB[c4 + 2], v.z, AB[128 + c4 + 2]);
  v.w = fmaf(AB[c4 + 3], v.w, AB[128 + c4 + 3]);
  ((float4*)out)[i] = v;
}

// ---------------------------------------------------------------------------
extern "C" void kernel_launch(void* const* d_in, const int* in_sizes, int n_in,
                              void* d_out, int out_size, void* d_ws,
                              size_t ws_size, hipStream_t stream) {
  const float* x = (const float*)d_in[0];
  const int* ei = (const int*)d_in[1];
  const float* Wl = (const float*)d_in[2];
  const float* Wr = (const float*)d_in[3];
  const float* att = (const float*)d_in[4];
  const float* bias = (const float*)d_in[5];
  const float* gw = (const float*)d_in[6];
  const float* gb = (const float*)d_in[7];
  const float* gms = (const float*)d_in[8];
  float* out = (float*)d_out;

  const int n = in_sizes[0] / 128;
  const int e = in_sizes[1] / 2;
  const int nchunk = (n + 255) / 256;
  const int nb = (n + 15) >> BSHIFT;  // buckets of 16 nodes
  const int GN_BLOCKS = 256;

  char* w = (char*)d_ws;
  auto alloc = [&](size_t bytes) {
    char* p = w;
    w += (bytes + 255) & ~(size_t)255;
    return p;
  };
  float* xl = (float*)alloc((size_t)n * 128 * sizeof(float));
  float* xr = (float*)alloc((size_t)n * 128 * sizeof(float));
  int* count = (int*)alloc((size_t)n * sizeof(int));
  int* offsets = (int*)alloc((size_t)(n + 1) * sizeof(int));
  int* cursor = (int*)alloc((size_t)n * sizeof(int));
  int* csr_src = (int*)alloc((size_t)e * sizeof(int));
  unsigned int* ebuf = (unsigned int*)alloc((size_t)e * sizeof(int));
  int* bcur = (int*)alloc((size_t)nb * sizeof(int));
  int* chunkSum = (int*)alloc((size_t)nchunk * sizeof(int));
  int* chunkOff = (int*)alloc((size_t)nchunk * sizeof(int));
  float* part = (float*)alloc((size_t)GN_BLOCKS * 256 * sizeof(float));
  float* AB = (float*)alloc(256 * sizeof(float));

  hipMemsetAsync(count, 0, (size_t)n * sizeof(int), stream);

  gemm_xw<<<(n + 31) / 32, 256, 0, stream>>>(x, Wl, Wr, xl, xr, n);
  hist_kernel<<<(e + 255) / 256, 256, 0, stream>>>(ei, count, e);
  scan_chunks<<<nchunk, 256, 0, stream>>>(count, chunkSum, n);
  scan_top<<<1, 256, 0, stream>>>(chunkSum, chunkOff, nchunk);
  scan_fill<<<nchunk, 256, 0, stream>>>(count, chunkOff, offsets, cursor, n, e);
  init_bcur<<<(nb + 255) / 256, 256, 0, stream>>>(offsets, bcur, nb, n);
  bucketize<<<(e + 255) / 256, 256, 0, stream>>>(ei, bcur, ebuf, e);
  bucket_scatter<<<nb, 256, 0, stream>>>(ebuf, offsets, cursor, csr_src, n);
  node_agg<<<(n + 3) / 4, 256, 0, stream>>>(xl, xr, offsets, csr_src, att, bias,
                                            out, n);
  gn_partial<<<GN_BLOCKS, 256, 0, stream>>>(out, part, n * 128);
  gn_final<<<1, 128, 0, stream>>>(part, gw, gb, gms, AB, GN_BLOCKS,
                                  1.0f / (float)n);
  gn_apply<<<(n * 32 + 255) / 256, 256, 0, stream>>>(out, AB, n * 32);
}

// Round 5
// 427.213 us; speedup vs baseline: 1.4587x; 1.4587x over previous
//
#include <hip/hip_runtime.h>
#include <math.h>

// N=50000, E=1600000, F_IN=128, C_OUT=64, HEADS=2, HC=128
#define NEG_SLOPE 0.2f
#define GN_EPS 1e-5f
#define NBSHIFT 8        // 256 nodes per coarse bucket
#define CHUNK 8192       // edges per partition block

// ---------------------------------------------------------------------------
// K1: xl = x @ W_l, xr = x @ W_r.  Block = 256 thr, tile 32 rows x 256 cols.
// ---------------------------------------------------------------------------
__global__ __launch_bounds__(256) void gemm_xw(
    const float* __restrict__ x, const float* __restrict__ Wl,
    const float* __restrict__ Wr, float* __restrict__ xl,
    float* __restrict__ xr, int n) {
  __shared__ float xs[32][128];
  const int tid = threadIdx.x;
  const int r0 = blockIdx.x * 32;
  const int rows = min(32, n - r0);

#pragma unroll
  for (int j = 0; j < 4; ++j) {
    int f4 = j * 256 + tid;
    int row = f4 >> 5;
    int c4 = f4 & 31;
    float4 v = make_float4(0.f, 0.f, 0.f, 0.f);
    if (row < rows) v = ((const float4*)(x + (size_t)(r0 + row) * 128))[c4];
    ((float4*)&xs[row][0])[c4] = v;
  }
  __syncthreads();

  const int rg = tid >> 6;
  const int cg = tid & 63;
  const float* __restrict__ W = (cg < 32) ? Wl : Wr;
  const int cb = (cg < 32) ? 4 * cg : 4 * cg - 128;

  float4 acc[8];
#pragma unroll
  for (int r = 0; r < 8; ++r) acc[r] = make_float4(0.f, 0.f, 0.f, 0.f);

#pragma unroll 4
  for (int k4 = 0; k4 < 32; ++k4) {
    float4 xv[8];
#pragma unroll
    for (int r = 0; r < 8; ++r)
      xv[r] = *(const float4*)&xs[rg * 8 + r][k4 * 4];
    float4 w0 = *(const float4*)(W + (size_t)(4 * k4 + 0) * 128 + cb);
    float4 w1 = *(const float4*)(W + (size_t)(4 * k4 + 1) * 128 + cb);
    float4 w2 = *(const float4*)(W + (size_t)(4 * k4 + 2) * 128 + cb);
    float4 w3 = *(const float4*)(W + (size_t)(4 * k4 + 3) * 128 + cb);
#pragma unroll
    for (int r = 0; r < 8; ++r) {
      acc[r].x = fmaf(xv[r].x, w0.x, acc[r].x);
      acc[r].y = fmaf(xv[r].x, w0.y, acc[r].y);
      acc[r].z = fmaf(xv[r].x, w0.z, acc[r].z);
      acc[r].w = fmaf(xv[r].x, w0.w, acc[r].w);
      acc[r].x = fmaf(xv[r].y, w1.x, acc[r].x);
      acc[r].y = fmaf(xv[r].y, w1.y, acc[r].y);
      acc[r].z = fmaf(xv[r].y, w1.z, acc[r].z);
      acc[r].w = fmaf(xv[r].y, w1.w, acc[r].w);
      acc[r].x = fmaf(xv[r].z, w2.x, acc[r].x);
      acc[r].y = fmaf(xv[r].z, w2.y, acc[r].y);
      acc[r].z = fmaf(xv[r].z, w2.z, acc[r].z);
      acc[r].w = fmaf(xv[r].z, w2.w, acc[r].w);
      acc[r].x = fmaf(xv[r].w, w3.x, acc[r].x);
      acc[r].y = fmaf(xv[r].w, w3.y, acc[r].y);
      acc[r].z = fmaf(xv[r].w, w3.z, acc[r].z);
      acc[r].w = fmaf(xv[r].w, w3.w, acc[r].w);
    }
  }

  float* __restrict__ dst = (cg < 32) ? xl : xr;
#pragma unroll
  for (int r = 0; r < 8; ++r) {
    int row = rg * 8 + r;
    if (row < rows)
      *(float4*)(dst + (size_t)(r0 + row) * 128 + cb) = acc[r];
  }
}

// ---------------------------------------------------------------------------
// K2: coarse histogram (196 buckets of 256 nodes) via LDS, tiny global merge
// ---------------------------------------------------------------------------
__global__ __launch_bounds__(256) void coarse_hist(const int* __restrict__ ei,
                                                   int* __restrict__ bhist,
                                                   int e) {
  __shared__ int hist[256];
  hist[threadIdx.x] = 0;
  __syncthreads();
  const int stride = gridDim.x * 256;
  for (int i = blockIdx.x * 256 + threadIdx.x; i < e; i += stride)
    atomicAdd(&hist[ei[e + i] >> NBSHIFT], 1);
  __syncthreads();
  int v = hist[threadIdx.x];
  if (v > 0) atomicAdd(&bhist[threadIdx.x], v);
}

// ---------------------------------------------------------------------------
// K3: exclusive scan of bucket counts -> bbase[nb+1], init gcur, sentinel
// ---------------------------------------------------------------------------
__global__ __launch_bounds__(256) void bscan(const int* __restrict__ bhist,
                                             int* __restrict__ bbase,
                                             int* __restrict__ gcur,
                                             int* __restrict__ offsets, int nb,
                                             int n, int e) {
  __shared__ int sd[256];
  int t = threadIdx.x;
  int v = (t < nb) ? bhist[t] : 0;
  sd[t] = v;
  __syncthreads();
#pragma unroll
  for (int s = 1; s < 256; s <<= 1) {
    int add = (t >= s) ? sd[t - s] : 0;
    __syncthreads();
    sd[t] += add;
    __syncthreads();
  }
  int excl = sd[t] - v;
  if (t < nb) {
    bbase[t] = excl;
    gcur[t] = excl;
  } else {
    gcur[t] = 0;
  }
  if (t == 0) {
    bbase[nb] = e;
    offsets[n] = e;
  }
}

// ---------------------------------------------------------------------------
// K4: partition. Each block owns CHUNK edges: LDS histogram over buckets,
// claims ONE contiguous run per bucket (single atomicAdd), then writes its
// edges into its own runs. Every L2 line of a run has a single writing
// block -> full-line writebacks (fix for R3/R4's 80-100MB partial-line
// thrash). Packed entry: src (16b) | local_dst (8b) << 16.
// ---------------------------------------------------------------------------
__global__ __launch_bounds__(256) void partition(const int* __restrict__ ei,
                                                 int* __restrict__ gcur,
                                                 unsigned int* __restrict__ ebuf,
                                                 int e) {
  __shared__ int hist[256];
  __shared__ int lcur[256];
  const int t = threadIdx.x;
  const int c0 = blockIdx.x * CHUNK;
  const int cend = min(c0 + CHUNK, e);
  hist[t] = 0;
  __syncthreads();
  for (int i = c0 + t; i < cend; i += 256)
    atomicAdd(&hist[ei[e + i] >> NBSHIFT], 1);
  __syncthreads();
  lcur[t] = atomicAdd(&gcur[t], hist[t]);  // cnt==0 -> harmless claim of 0
  __syncthreads();
  for (int i = c0 + t; i < cend; i += 256) {
    int dst = ei[e + i];
    int src = ei[i];
    int b = dst >> NBSHIFT;
    int pos = atomicAdd(&lcur[b], 1);
    ebuf[pos] = (unsigned int)src | ((unsigned int)(dst & 255) << 16);
  }
}

// ---------------------------------------------------------------------------
// K5: per-bucket CSR build. One block per coarse bucket: LDS node-histogram,
// LDS scan -> node offsets (written to global), LDS cursors -> scatter src
// into the bucket's private ~32KB csr window (single-XCD writer).
// Replaces hist_kernel + 3 scan kernels + global-cursor scatter.
// ---------------------------------------------------------------------------
__global__ __launch_bounds__(256) void csr_build(
    const unsigned int* __restrict__ ebuf, const int* __restrict__ bbase,
    int* __restrict__ offsets, int* __restrict__ csr_src, int n) {
  __shared__ int hist[256];
  __shared__ int sc[256];
  const int b = blockIdx.x;
  const int t = threadIdx.x;
  const int node0 = b << NBSHIFT;
  const int seg0 = bbase[b];
  const int seg1 = bbase[b + 1];

  hist[t] = 0;
  __syncthreads();
  for (int i = seg0 + t; i < seg1; i += 256)
    atomicAdd(&hist[(ebuf[i] >> 16) & 255], 1);
  __syncthreads();
  int v = hist[t];
  sc[t] = v;
  __syncthreads();
#pragma unroll
  for (int s = 1; s < 256; s <<= 1) {
    int add = (t >= s) ? sc[t - s] : 0;
    __syncthreads();
    sc[t] += add;
    __syncthreads();
  }
  int start = seg0 + sc[t] - v;  // exclusive
  int node = node0 + t;
  if (node < n) offsets[node] = start;
  __syncthreads();
  hist[t] = start;  // reuse as cursor
  __syncthreads();
  for (int i = seg0 + t; i < seg1; i += 256) {
    unsigned int u = ebuf[i];
    int pos = atomicAdd(&hist[(u >> 16) & 255], 1);
    csr_src[pos] = (int)(u & 0xFFFFu);
  }
}

// ---------------------------------------------------------------------------
// K6: per-node softmax attention + aggregation (unchanged from R3 — worked).
// ---------------------------------------------------------------------------
__global__ __launch_bounds__(256) void node_agg(
    const float* __restrict__ xl, const float* __restrict__ xr,
    const int* __restrict__ offsets, const int* __restrict__ csr_src,
    const float* __restrict__ att, const float* __restrict__ bias,
    float* __restrict__ out, int n) {
  const int wave = threadIdx.x >> 6;
  const int lane = threadIdx.x & 63;
  const int node = blockIdx.x * 4 + wave;
  if (node >= n) return;
  const int ch = lane * 2;

  const float2 xr2 = *(const float2*)(xr + (size_t)node * 128 + ch);
  const float2 a2 = *(const float2*)(att + ch);

  const int start = offsets[node];
  const int end = offsets[node + 1];

  float s = 0.f;
  float2 acc = make_float2(0.f, 0.f);

  auto edge_body = [&](float2 v) {
    float t0 = v.x + xr2.x;
    float t1 = v.y + xr2.y;
    t0 = fmaxf(t0, 0.f) + NEG_SLOPE * fminf(t0, 0.f);
    t1 = fmaxf(t1, 0.f) + NEG_SLOPE * fminf(t1, 0.f);
    float p = fmaf(t0, a2.x, t1 * a2.y);
    p += __shfl_xor(p, 1, 64);
    p += __shfl_xor(p, 2, 64);
    p += __shfl_xor(p, 4, 64);
    p += __shfl_xor(p, 8, 64);
    p += __shfl_xor(p, 16, 64);
    float w = __expf(p);
    s += w;
    acc.x = fmaf(w, v.x, acc.x);
    acc.y = fmaf(w, v.y, acc.y);
  };

  edge_body(*(const float2*)(xl + (size_t)node * 128 + ch));

  int e = start;
  for (; e + 1 < end; e += 2) {
    int src0 = csr_src[e];
    int src1 = csr_src[e + 1];
    float2 va = *(const float2*)(xl + (size_t)src0 * 128 + ch);
    float2 vb = *(const float2*)(xl + (size_t)src1 * 128 + ch);
    edge_body(va);
    edge_body(vb);
  }
  if (e < end) {
    int src0 = csr_src[e];
    edge_body(*(const float2*)(xl + (size_t)src0 * 128 + ch));
  }

  const float inv = 1.f / s;
  const float2 b2 = *(const float2*)(bias + ch);
  float2 o = make_float2(fmaf(acc.x, inv, b2.x), fmaf(acc.y, inv, b2.y));
  *(float2*)(out + (size_t)node * 128 + ch) = o;
}

// ---------------------------------------------------------------------------
// K7a: per-channel sum & sumsq partials
// ---------------------------------------------------------------------------
__global__ __launch_bounds__(256) void gn_partial(const float* __restrict__ out,
                                                  float* __restrict__ part,
                                                  int total) {
  float s = 0.f, q = 0.f;
  const int stride = gridDim.x * 256;
  for (int idx = blockIdx.x * 256 + threadIdx.x; idx < total; idx += stride) {
    float v = out[idx];
    s += v;
    q = fmaf(v, v, q);
  }
  __shared__ float sd[256], qd[256];
  sd[threadIdx.x] = s;
  qd[threadIdx.x] = q;
  __syncthreads();
  if (threadIdx.x < 128) {
    part[blockIdx.x * 256 + threadIdx.x] = sd[threadIdx.x] + sd[threadIdx.x + 128];
    part[blockIdx.x * 256 + 128 + threadIdx.x] =
        qd[threadIdx.x] + qd[threadIdx.x + 128];
  }
}

// K7b: combine partials, produce affine params A,B
__global__ void gn_final(const float* __restrict__ part,
                         const float* __restrict__ gw,
                         const float* __restrict__ gb,
                         const float* __restrict__ gms, float* __restrict__ AB,
                         int nblocks, float inv_n) {
  int c = threadIdx.x;  // 128 threads
  float S = 0.f, Q = 0.f;
  for (int b = 0; b < nblocks; ++b) {
    S += part[b * 256 + c];
    Q += part[b * 256 + 128 + c];
  }
  float mean = S * inv_n;
  float msc = mean * gms[c];
  float var = Q * inv_n - 2.f * msc * mean + msc * msc;
  float scale = gw[c] * rsqrtf(var + GN_EPS);
  AB[c] = scale;
  AB[128 + c] = gb[c] - scale * msc;
}

// K7c: in-place normalize, float4-vectorized
__global__ void gn_apply(float* __restrict__ out, const float* __restrict__ AB,
                         int total4) {
  int i = blockIdx.x * blockDim.x + threadIdx.x;
  if (i >= total4) return;
  float4 v = ((float4*)out)[i];
  int c4 = (i & 31) * 4;
  v.x = fmaf(AB[c4 + 0], v.x, AB[128 + c4 + 0]);
  v.y = fmaf(AB[c4 + 1], v.y, AB[128 + c4 + 1]);
  v.z = fmaf(AB[c4 + 2], v.z, AB[128 + c4 + 2]);
  v.w = fmaf(AB[c4 + 3], v.w, AB[128 + c4 + 3]);
  ((float4*)out)[i] = v;
}

// ---------------------------------------------------------------------------
extern "C" void kernel_launch(void* const* d_in, const int* in_sizes, int n_in,
                              void* d_out, int out_size, void* d_ws,
                              size_t ws_size, hipStream_t stream) {
  const float* x = (const float*)d_in[0];
  const int* ei = (const int*)d_in[1];
  const float* Wl = (const float*)d_in[2];
  const float* Wr = (const float*)d_in[3];
  const float* att = (const float*)d_in[4];
  const float* bias = (const float*)d_in[5];
  const float* gw = (const float*)d_in[6];
  const float* gb = (const float*)d_in[7];
  const float* gms = (const float*)d_in[8];
  float* out = (float*)d_out;

  const int n = in_sizes[0] / 128;
  const int e = in_sizes[1] / 2;
  const int nb = (n + 255) >> NBSHIFT;       // coarse buckets (196)
  const int nchunks = (e + CHUNK - 1) / CHUNK;
  const int GN_BLOCKS = 256;

  char* w = (char*)d_ws;
  auto alloc = [&](size_t bytes) {
    char* p = w;
    w += (bytes + 255) & ~(size_t)255;
    return p;
  };
  float* xl = (float*)alloc((size_t)n * 128 * sizeof(float));
  float* xr = (float*)alloc((size_t)n * 128 * sizeof(float));
  int* offsets = (int*)alloc((size_t)(n + 1) * sizeof(int));
  int* csr_src = (int*)alloc((size_t)e * sizeof(int));
  unsigned int* ebuf = (unsigned int*)alloc((size_t)e * sizeof(int));
  int* bhist = (int*)alloc(256 * sizeof(int));
  int* bbase = (int*)alloc((size_t)(nb + 1) * sizeof(int));
  int* gcur = (int*)alloc(256 * sizeof(int));
  float* part = (float*)alloc((size_t)GN_BLOCKS * 256 * sizeof(float));
  float* AB = (float*)alloc(256 * sizeof(float));

  hipMemsetAsync(bhist, 0, 256 * sizeof(int), stream);

  gemm_xw<<<(n + 31) / 32, 256, 0, stream>>>(x, Wl, Wr, xl, xr, n);
  coarse_hist<<<196, 256, 0, stream>>>(ei, bhist, e);
  bscan<<<1, 256, 0, stream>>>(bhist, bbase, gcur, offsets, nb, n, e);
  partition<<<nchunks, 256, 0, stream>>>(ei, gcur, ebuf, e);
  csr_build<<<nb, 256, 0, stream>>>(ebuf, bbase, offsets, csr_src, n);
  node_agg<<<(n + 3) / 4, 256, 0, stream>>>(xl, xr, offsets, csr_src, att, bias,
                                            out, n);
  gn_partial<<<GN_BLOCKS, 256, 0, stream>>>(out, part, n * 128);
  gn_final<<<1, 128, 0, stream>>>(part, gw, gb, gms, AB, GN_BLOCKS,
                                  1.0f / (float)n);
  gn_apply<<<(n * 32 + 255) / 256, 256, 0, stream>>>(out, AB, n * 32);
}

// Round 6
// 412.919 us; speedup vs baseline: 1.5092x; 1.0346x over previous
//
#include <hip/hip_runtime.h>
#include <math.h>

// N=50000, E=1600000, F_IN=128, C_OUT=64, HEADS=2, HC=128
#define NEG_SLOPE 0.2f
#define GN_EPS 1e-5f
#define NBSHIFT 8        // 256 nodes per coarse bucket
#define CHUNK 8192       // edges per partition block

__device__ __forceinline__ int rfl(int v) {
  return __builtin_amdgcn_readfirstlane(v);
}

// ---------------------------------------------------------------------------
// K1: xl = x @ W_l, xr = x @ W_r.  Block = 256 thr, tile 32 rows x 256 cols.
// ---------------------------------------------------------------------------
__global__ __launch_bounds__(256) void gemm_xw(
    const float* __restrict__ x, const float* __restrict__ Wl,
    const float* __restrict__ Wr, float* __restrict__ xl,
    float* __restrict__ xr, int n) {
  __shared__ float xs[32][128];
  const int tid = threadIdx.x;
  const int r0 = blockIdx.x * 32;
  const int rows = min(32, n - r0);

#pragma unroll
  for (int j = 0; j < 4; ++j) {
    int f4 = j * 256 + tid;
    int row = f4 >> 5;
    int c4 = f4 & 31;
    float4 v = make_float4(0.f, 0.f, 0.f, 0.f);
    if (row < rows) v = ((const float4*)(x + (size_t)(r0 + row) * 128))[c4];
    ((float4*)&xs[row][0])[c4] = v;
  }
  __syncthreads();

  const int rg = tid >> 6;
  const int cg = tid & 63;
  const float* __restrict__ W = (cg < 32) ? Wl : Wr;
  const int cb = (cg < 32) ? 4 * cg : 4 * cg - 128;

  float4 acc[8];
#pragma unroll
  for (int r = 0; r < 8; ++r) acc[r] = make_float4(0.f, 0.f, 0.f, 0.f);

#pragma unroll 4
  for (int k4 = 0; k4 < 32; ++k4) {
    float4 xv[8];
#pragma unroll
    for (int r = 0; r < 8; ++r)
      xv[r] = *(const float4*)&xs[rg * 8 + r][k4 * 4];
    float4 w0 = *(const float4*)(W + (size_t)(4 * k4 + 0) * 128 + cb);
    float4 w1 = *(const float4*)(W + (size_t)(4 * k4 + 1) * 128 + cb);
    float4 w2 = *(const float4*)(W + (size_t)(4 * k4 + 2) * 128 + cb);
    float4 w3 = *(const float4*)(W + (size_t)(4 * k4 + 3) * 128 + cb);
#pragma unroll
    for (int r = 0; r < 8; ++r) {
      acc[r].x = fmaf(xv[r].x, w0.x, acc[r].x);
      acc[r].y = fmaf(xv[r].x, w0.y, acc[r].y);
      acc[r].z = fmaf(xv[r].x, w0.z, acc[r].z);
      acc[r].w = fmaf(xv[r].x, w0.w, acc[r].w);
      acc[r].x = fmaf(xv[r].y, w1.x, acc[r].x);
      acc[r].y = fmaf(xv[r].y, w1.y, acc[r].y);
      acc[r].z = fmaf(xv[r].y, w1.z, acc[r].z);
      acc[r].w = fmaf(xv[r].y, w1.w, acc[r].w);
      acc[r].x = fmaf(xv[r].z, w2.x, acc[r].x);
      acc[r].y = fmaf(xv[r].z, w2.y, acc[r].y);
      acc[r].z = fmaf(xv[r].z, w2.z, acc[r].z);
      acc[r].w = fmaf(xv[r].z, w2.w, acc[r].w);
      acc[r].x = fmaf(xv[r].w, w3.x, acc[r].x);
      acc[r].y = fmaf(xv[r].w, w3.y, acc[r].y);
      acc[r].z = fmaf(xv[r].w, w3.z, acc[r].z);
      acc[r].w = fmaf(xv[r].w, w3.w, acc[r].w);
    }
  }

  float* __restrict__ dst = (cg < 32) ? xl : xr;
#pragma unroll
  for (int r = 0; r < 8; ++r) {
    int row = rg * 8 + r;
    if (row < rows)
      *(float4*)(dst + (size_t)(r0 + row) * 128 + cb) = acc[r];
  }
}

// ---------------------------------------------------------------------------
// K2: coarse histogram (196 buckets of 256 nodes) via LDS, tiny global merge
// ---------------------------------------------------------------------------
__global__ __launch_bounds__(256) void coarse_hist(const int* __restrict__ ei,
                                                   int* __restrict__ bhist,
                                                   int e) {
  __shared__ int hist[256];
  hist[threadIdx.x] = 0;
  __syncthreads();
  const int stride = gridDim.x * 256;
  for (int i = blockIdx.x * 256 + threadIdx.x; i < e; i += stride)
    atomicAdd(&hist[ei[e + i] >> NBSHIFT], 1);
  __syncthreads();
  int v = hist[threadIdx.x];
  if (v > 0) atomicAdd(&bhist[threadIdx.x], v);
}

// ---------------------------------------------------------------------------
// K3: exclusive scan of bucket counts -> bbase[nb+1], init gcur, sentinel
// ---------------------------------------------------------------------------
__global__ __launch_bounds__(256) void bscan(const int* __restrict__ bhist,
                                             int* __restrict__ bbase,
                                             int* __restrict__ gcur,
                                             int* __restrict__ offsets, int nb,
                                             int n, int e) {
  __shared__ int sd[256];
  int t = threadIdx.x;
  int v = (t < nb) ? bhist[t] : 0;
  sd[t] = v;
  __syncthreads();
#pragma unroll
  for (int s = 1; s < 256; s <<= 1) {
    int add = (t >= s) ? sd[t - s] : 0;
    __syncthreads();
    sd[t] += add;
    __syncthreads();
  }
  int excl = sd[t] - v;
  if (t < nb) {
    bbase[t] = excl;
    gcur[t] = excl;
  } else {
    gcur[t] = 0;
  }
  if (t == 0) {
    bbase[nb] = e;
    offsets[n] = e;
  }
}

// ---------------------------------------------------------------------------
// K4: partition. Each block owns CHUNK edges: LDS histogram over buckets,
// claims ONE contiguous run per bucket (single atomicAdd), then writes its
// edges into its own runs (single writer per L2 line -> full-line
// writebacks). Packed entry: src (16b) | local_dst (8b) << 16.
// ---------------------------------------------------------------------------
__global__ __launch_bounds__(256) void partition(const int* __restrict__ ei,
                                                 int* __restrict__ gcur,
                                                 unsigned int* __restrict__ ebuf,
                                                 int e) {
  __shared__ int hist[256];
  __shared__ int lcur[256];
  const int t = threadIdx.x;
  const int c0 = blockIdx.x * CHUNK;
  const int cend = min(c0 + CHUNK, e);
  hist[t] = 0;
  __syncthreads();
  for (int i = c0 + t; i < cend; i += 256)
    atomicAdd(&hist[ei[e + i] >> NBSHIFT], 1);
  __syncthreads();
  lcur[t] = atomicAdd(&gcur[t], hist[t]);
  __syncthreads();
  for (int i = c0 + t; i < cend; i += 256) {
    int dst = ei[e + i];
    int src = ei[i];
    int b = dst >> NBSHIFT;
    int pos = atomicAdd(&lcur[b], 1);
    ebuf[pos] = (unsigned int)src | ((unsigned int)(dst & 255) << 16);
  }
}

// ---------------------------------------------------------------------------
// K5: per-bucket CSR build. One block per coarse bucket: LDS node-histogram,
// LDS scan -> node offsets, LDS cursors -> scatter src into the bucket's
// private ~32KB csr window.
// ---------------------------------------------------------------------------
__global__ __launch_bounds__(256) void csr_build(
    const unsigned int* __restrict__ ebuf, const int* __restrict__ bbase,
    int* __restrict__ offsets, int* __restrict__ csr_src, int n) {
  __shared__ int hist[256];
  __shared__ int sc[256];
  const int b = blockIdx.x;
  const int t = threadIdx.x;
  const int node0 = b << NBSHIFT;
  const int seg0 = bbase[b];
  const int seg1 = bbase[b + 1];

  hist[t] = 0;
  __syncthreads();
  for (int i = seg0 + t; i < seg1; i += 256)
    atomicAdd(&hist[(ebuf[i] >> 16) & 255], 1);
  __syncthreads();
  int v = hist[t];
  sc[t] = v;
  __syncthreads();
#pragma unroll
  for (int s = 1; s < 256; s <<= 1) {
    int add = (t >= s) ? sc[t - s] : 0;
    __syncthreads();
    sc[t] += add;
    __syncthreads();
  }
  int start = seg0 + sc[t] - v;  // exclusive
  int node = node0 + t;
  if (node < n) offsets[node] = start;
  __syncthreads();
  hist[t] = start;  // reuse as cursor
  __syncthreads();
  for (int i = seg0 + t; i < seg1; i += 256) {
    unsigned int u = ebuf[i];
    int pos = atomicAdd(&hist[(u >> 16) & 255], 1);
    csr_src[pos] = (int)(u & 0xFFFFu);
  }
}

// ---------------------------------------------------------------------------
// K6: per-node softmax attention + aggregation.
// One wave per node. Lane l owns channel pair (2l, 2l+1): lanes 0..31 =
// head0, lanes 32..63 = head1.
// R6: (a) paired-edge butterfly — after xor1, edge-a's logit packs into even
// lanes, edge-b's into odd (masks 2/4/8/16 preserve parity): 7 shfl + 1 exp
// per 2 edges vs 10 + 2. (b) readfirstlane scalarizes bounds and src
// indices -> gather address math moves to SALU.
// ---------------------------------------------------------------------------
__global__ __launch_bounds__(256) void node_agg(
    const float* __restrict__ xl, const float* __restrict__ xr,
    const int* __restrict__ offsets, const int* __restrict__ csr_src,
    const float* __restrict__ att, const float* __restrict__ bias,
    float* __restrict__ out, int n) {
  const int wave = threadIdx.x >> 6;
  const int lane = threadIdx.x & 63;
  const int node = blockIdx.x * 4 + wave;
  if (node >= n) return;
  const int ch = lane * 2;

  const float2 xr2 = *(const float2*)(xr + (size_t)node * 128 + ch);
  const float2 a2 = *(const float2*)(att + ch);
  const float2* __restrict__ xlp = (const float2*)xl + lane;  // + 64*src

  const int start = rfl(offsets[node]);
  const int end = rfl(offsets[node + 1]);

  float s = 0.f;
  float2 acc = make_float2(0.f, 0.f);

  // per-lane partial logit for one edge value
  auto partial = [&](float2 v) {
    float t0 = v.x + xr2.x;
    float t1 = v.y + xr2.y;
    t0 = fmaxf(t0, 0.f) + NEG_SLOPE * fminf(t0, 0.f);
    t1 = fmaxf(t1, 0.f) + NEG_SLOPE * fminf(t1, 0.f);
    return fmaf(t0, a2.x, t1 * a2.y);
  };

  auto single_body = [&](float2 v) {
    float p = partial(v);
    p += __shfl_xor(p, 1, 64);
    p += __shfl_xor(p, 2, 64);
    p += __shfl_xor(p, 4, 64);
    p += __shfl_xor(p, 8, 64);
    p += __shfl_xor(p, 16, 64);
    float w = __expf(p);
    s += w;
    acc.x = fmaf(w, v.x, acc.x);
    acc.y = fmaf(w, v.y, acc.y);
  };

  auto pair_body = [&](float2 va, float2 vb) {
    float pa = partial(va);
    float pb = partial(vb);
    pa += __shfl_xor(pa, 1, 64);
    pb += __shfl_xor(pb, 1, 64);
    float z = (lane & 1) ? pb : pa;   // even lanes: a, odd lanes: b
    z += __shfl_xor(z, 2, 64);
    z += __shfl_xor(z, 4, 64);
    z += __shfl_xor(z, 8, 64);
    z += __shfl_xor(z, 16, 64);
    float ew = __expf(z);
    float eo = __shfl_xor(ew, 1, 64);
    float wa = (lane & 1) ? eo : ew;
    float wb = (lane & 1) ? ew : eo;
    s += wa + wb;
    acc.x = fmaf(wa, va.x, acc.x);
    acc.y = fmaf(wa, va.y, acc.y);
    acc.x = fmaf(wb, vb.x, acc.x);
    acc.y = fmaf(wb, vb.y, acc.y);
  };

  const float2 vself = xlp[(size_t)node * 64];
  int e = start;
  if ((end - start) & 1) {  // odd in-degree: pair self-loop with first edge
    int s1 = rfl(csr_src[e]);
    ++e;
    pair_body(vself, xlp[(size_t)s1 * 64]);
  } else {
    single_body(vself);
  }
#pragma unroll 2
  for (; e < end; e += 2) {
    int s0 = rfl(csr_src[e]);
    int s1 = rfl(csr_src[e + 1]);
    float2 va = xlp[(size_t)s0 * 64];
    float2 vb = xlp[(size_t)s1 * 64];
    pair_body(va, vb);
  }

  const float inv = 1.f / s;
  const float2 b2 = *(const float2*)(bias + ch);
  float2 o = make_float2(fmaf(acc.x, inv, b2.x), fmaf(acc.y, inv, b2.y));
  *(float2*)(out + (size_t)node * 128 + ch) = o;
}

// ---------------------------------------------------------------------------
// K7a: per-channel sum & sumsq partials
// ---------------------------------------------------------------------------
__global__ __launch_bounds__(256) void gn_partial(const float* __restrict__ out,
                                                  float* __restrict__ part,
                                                  int total) {
  float s = 0.f, q = 0.f;
  const int stride = gridDim.x * 256;
  for (int idx = blockIdx.x * 256 + threadIdx.x; idx < total; idx += stride) {
    float v = out[idx];
    s += v;
    q = fmaf(v, v, q);
  }
  __shared__ float sd[256], qd[256];
  sd[threadIdx.x] = s;
  qd[threadIdx.x] = q;
  __syncthreads();
  if (threadIdx.x < 128) {
    part[blockIdx.x * 256 + threadIdx.x] = sd[threadIdx.x] + sd[threadIdx.x + 128];
    part[blockIdx.x * 256 + 128 + threadIdx.x] =
        qd[threadIdx.x] + qd[threadIdx.x + 128];
  }
}

// K7b: combine partials, produce affine params A,B
__global__ void gn_final(const float* __restrict__ part,
                         const float* __restrict__ gw,
                         const float* __restrict__ gb,
                         const float* __restrict__ gms, float* __restrict__ AB,
                         int nblocks, float inv_n) {
  int c = threadIdx.x;  // 128 threads
  float S = 0.f, Q = 0.f;
  for (int b = 0; b < nblocks; ++b) {
    S += part[b * 256 + c];
    Q += part[b * 256 + 128 + c];
  }
  float mean = S * inv_n;
  float msc = mean * gms[c];
  float var = Q * inv_n - 2.f * msc * mean + msc * msc;
  float scale = gw[c] * rsqrtf(var + GN_EPS);
  AB[c] = scale;
  AB[128 + c] = gb[c] - scale * msc;
}

// K7c: in-place normalize, float4-vectorized
__global__ void gn_apply(float* __restrict__ out, const float* __restrict__ AB,
                         int total4) {
  int i = blockIdx.x * blockDim.x + threadIdx.x;
  if (i >= total4) return;
  float4 v = ((float4*)out)[i];
  int c4 = (i & 31) * 4;
  v.x = fmaf(AB[c4 + 0], v.x, AB[128 + c4 + 0]);
  v.y = fmaf(AB[c4 + 1], v.y, AB[128 + c4 + 1]);
  v.z = fmaf(AB[c4 + 2], v.z, AB[128 + c4 + 2]);
  v.w = fmaf(AB[c4 + 3], v.w, AB[128 + c4 + 3]);
  ((float4*)out)[i] = v;
}

// ---------------------------------------------------------------------------
extern "C" void kernel_launch(void* const* d_in, const int* in_sizes, int n_in,
                              void* d_out, int out_size, void* d_ws,
                              size_t ws_size, hipStream_t stream) {
  const float* x = (const float*)d_in[0];
  const int* ei = (const int*)d_in[1];
  const float* Wl = (const float*)d_in[2];
  const float* Wr = (const float*)d_in[3];
  const float* att = (const float*)d_in[4];
  const float* bias = (const float*)d_in[5];
  const float* gw = (const float*)d_in[6];
  const float* gb = (const float*)d_in[7];
  const float* gms = (const float*)d_in[8];
  float* out = (float*)d_out;

  const int n = in_sizes[0] / 128;
  const int e = in_sizes[1] / 2;
  const int nb = (n + 255) >> NBSHIFT;       // coarse buckets (196)
  const int nchunks = (e + CHUNK - 1) / CHUNK;
  const int GN_BLOCKS = 256;

  char* w = (char*)d_ws;
  auto alloc = [&](size_t bytes) {
    char* p = w;
    w += (bytes + 255) & ~(size_t)255;
    return p;
  };
  float* xl = (float*)alloc((size_t)n * 128 * sizeof(float));
  float* xr = (float*)alloc((size_t)n * 128 * sizeof(float));
  int* offsets = (int*)alloc((size_t)(n + 1) * sizeof(int));
  int* csr_src = (int*)alloc((size_t)e * sizeof(int));
  unsigned int* ebuf = (unsigned int*)alloc((size_t)e * sizeof(int));
  int* bhist = (int*)alloc(256 * sizeof(int));
  int* bbase = (int*)alloc((size_t)(nb + 1) * sizeof(int));
  int* gcur = (int*)alloc(256 * sizeof(int));
  float* part = (float*)alloc((size_t)GN_BLOCKS * 256 * sizeof(float));
  float* AB = (float*)alloc(256 * sizeof(float));

  hipMemsetAsync(bhist, 0, 256 * sizeof(int), stream);

  gemm_xw<<<(n + 31) / 32, 256, 0, stream>>>(x, Wl, Wr, xl, xr, n);
  coarse_hist<<<196, 256, 0, stream>>>(ei, bhist, e);
  bscan<<<1, 256, 0, stream>>>(bhist, bbase, gcur, offsets, nb, n, e);
  partition<<<nchunks, 256, 0, stream>>>(ei, gcur, ebuf, e);
  csr_build<<<nb, 256, 0, stream>>>(ebuf, bbase, offsets, csr_src, n);
  node_agg<<<(n + 3) / 4, 256, 0, stream>>>(xl, xr, offsets, csr_src, att, bias,
                                            out, n);
  gn_partial<<<GN_BLOCKS, 256, 0, stream>>>(out, part, n * 128);
  gn_final<<<1, 128, 0, stream>>>(part, gw, gb, gms, AB, GN_BLOCKS,
                                  1.0f / (float)n);
  gn_apply<<<(n * 32 + 255) / 256, 256, 0, stream>>>(out, AB, n * 32);
}

// Round 7
// 397.783 us; speedup vs baseline: 1.5666x; 1.0381x over previous
//
#include <hip/hip_runtime.h>
#include <math.h>

// N=50000, E=1600000, F_IN=128, C_OUT=64, HEADS=2, HC=128
#define NEG_SLOPE 0.2f
#define GN_EPS 1e-5f
#define NBSHIFT 8        // 256 nodes per coarse bucket
#define CHUNK 8192       // edges per partition block

__device__ __forceinline__ int rfl(int v) {
  return __builtin_amdgcn_readfirstlane(v);
}

// round-nearest-even f32 -> bf16 (top 16 bits)
__device__ __forceinline__ unsigned int bf16r(float f) {
  unsigned int u = __float_as_uint(f);
  return (u + 0x7fffu + ((u >> 16) & 1u)) >> 16;
}

// ---------------------------------------------------------------------------
// K1: xl(bf16-packed) = x @ W_l, xr(fp32) = x @ W_r.
// Block = 256 thr, tile 32 rows x 256 cols. xl consumer (node_agg) reads
// lane-pair dwords, so pack (ch 2l, ch 2l+1) into one uint.
// ---------------------------------------------------------------------------
__global__ __launch_bounds__(256) void gemm_xw(
    const float* __restrict__ x, const float* __restrict__ Wl,
    const float* __restrict__ Wr, unsigned int* __restrict__ xlb,
    float* __restrict__ xr, int n) {
  __shared__ float xs[32][128];
  const int tid = threadIdx.x;
  const int r0 = blockIdx.x * 32;
  const int rows = min(32, n - r0);

#pragma unroll
  for (int j = 0; j < 4; ++j) {
    int f4 = j * 256 + tid;
    int row = f4 >> 5;
    int c4 = f4 & 31;
    float4 v = make_float4(0.f, 0.f, 0.f, 0.f);
    if (row < rows) v = ((const float4*)(x + (size_t)(r0 + row) * 128))[c4];
    ((float4*)&xs[row][0])[c4] = v;
  }
  __syncthreads();

  const int rg = tid >> 6;
  const int cg = tid & 63;
  const float* __restrict__ W = (cg < 32) ? Wl : Wr;
  const int cb = (cg < 32) ? 4 * cg : 4 * cg - 128;

  float4 acc[8];
#pragma unroll
  for (int r = 0; r < 8; ++r) acc[r] = make_float4(0.f, 0.f, 0.f, 0.f);

#pragma unroll 4
  for (int k4 = 0; k4 < 32; ++k4) {
    float4 xv[8];
#pragma unroll
    for (int r = 0; r < 8; ++r)
      xv[r] = *(const float4*)&xs[rg * 8 + r][k4 * 4];
    float4 w0 = *(const float4*)(W + (size_t)(4 * k4 + 0) * 128 + cb);
    float4 w1 = *(const float4*)(W + (size_t)(4 * k4 + 1) * 128 + cb);
    float4 w2 = *(const float4*)(W + (size_t)(4 * k4 + 2) * 128 + cb);
    float4 w3 = *(const float4*)(W + (size_t)(4 * k4 + 3) * 128 + cb);
#pragma unroll
    for (int r = 0; r < 8; ++r) {
      acc[r].x = fmaf(xv[r].x, w0.x, acc[r].x);
      acc[r].y = fmaf(xv[r].x, w0.y, acc[r].y);
      acc[r].z = fmaf(xv[r].x, w0.z, acc[r].z);
      acc[r].w = fmaf(xv[r].x, w0.w, acc[r].w);
      acc[r].x = fmaf(xv[r].y, w1.x, acc[r].x);
      acc[r].y = fmaf(xv[r].y, w1.y, acc[r].y);
      acc[r].z = fmaf(xv[r].y, w1.z, acc[r].z);
      acc[r].w = fmaf(xv[r].y, w1.w, acc[r].w);
      acc[r].x = fmaf(xv[r].z, w2.x, acc[r].x);
      acc[r].y = fmaf(xv[r].z, w2.y, acc[r].y);
      acc[r].z = fmaf(xv[r].z, w2.z, acc[r].z);
      acc[r].w = fmaf(xv[r].z, w2.w, acc[r].w);
      acc[r].x = fmaf(xv[r].w, w3.x, acc[r].x);
      acc[r].y = fmaf(xv[r].w, w3.y, acc[r].y);
      acc[r].z = fmaf(xv[r].w, w3.z, acc[r].z);
      acc[r].w = fmaf(xv[r].w, w3.w, acc[r].w);
    }
  }

  if (cg < 32) {
    // xl: pack 4 channels -> 2 dwords of 2xbf16
#pragma unroll
    for (int r = 0; r < 8; ++r) {
      int row = rg * 8 + r;
      if (row < rows) {
        uint2 p;
        p.x = bf16r(acc[r].x) | (bf16r(acc[r].y) << 16);
        p.y = bf16r(acc[r].z) | (bf16r(acc[r].w) << 16);
        *(uint2*)(xlb + (size_t)(r0 + row) * 64 + (cb >> 1)) = p;
      }
    }
  } else {
#pragma unroll
    for (int r = 0; r < 8; ++r) {
      int row = rg * 8 + r;
      if (row < rows)
        *(float4*)(xr + (size_t)(r0 + row) * 128 + cb) = acc[r];
    }
  }
}

// ---------------------------------------------------------------------------
// K2: coarse histogram (196 buckets of 256 nodes) via LDS, tiny global merge
// ---------------------------------------------------------------------------
__global__ __launch_bounds__(256) void coarse_hist(const int* __restrict__ ei,
                                                   int* __restrict__ bhist,
                                                   int e) {
  __shared__ int hist[256];
  hist[threadIdx.x] = 0;
  __syncthreads();
  const int stride = gridDim.x * 256;
  for (int i = blockIdx.x * 256 + threadIdx.x; i < e; i += stride)
    atomicAdd(&hist[ei[e + i] >> NBSHIFT], 1);
  __syncthreads();
  int v = hist[threadIdx.x];
  if (v > 0) atomicAdd(&bhist[threadIdx.x], v);
}

// ---------------------------------------------------------------------------
// K3: exclusive scan of bucket counts -> bbase[nb+1], init gcur, sentinel
// ---------------------------------------------------------------------------
__global__ __launch_bounds__(256) void bscan(const int* __restrict__ bhist,
                                             int* __restrict__ bbase,
                                             int* __restrict__ gcur,
                                             int* __restrict__ offsets, int nb,
                                             int n, int e) {
  __shared__ int sd[256];
  int t = threadIdx.x;
  int v = (t < nb) ? bhist[t] : 0;
  sd[t] = v;
  __syncthreads();
#pragma unroll
  for (int s = 1; s < 256; s <<= 1) {
    int add = (t >= s) ? sd[t - s] : 0;
    __syncthreads();
    sd[t] += add;
    __syncthreads();
  }
  int excl = sd[t] - v;
  if (t < nb) {
    bbase[t] = excl;
    gcur[t] = excl;
  } else {
    gcur[t] = 0;
  }
  if (t == 0) {
    bbase[nb] = e;
    offsets[n] = e;
  }
}

// ---------------------------------------------------------------------------
// K4: partition. Each block owns CHUNK edges: LDS histogram over buckets,
// claims ONE contiguous run per bucket (single atomicAdd), then writes its
// edges into its own runs (single writer per L2 line -> full-line
// writebacks). Packed entry: src (16b) | local_dst (8b) << 16.
// ---------------------------------------------------------------------------
__global__ __launch_bounds__(256) void partition(const int* __restrict__ ei,
                                                 int* __restrict__ gcur,
                                                 unsigned int* __restrict__ ebuf,
                                                 int e) {
  __shared__ int hist[256];
  __shared__ int lcur[256];
  const int t = threadIdx.x;
  const int c0 = blockIdx.x * CHUNK;
  const int cend = min(c0 + CHUNK, e);
  hist[t] = 0;
  __syncthreads();
  for (int i = c0 + t; i < cend; i += 256)
    atomicAdd(&hist[ei[e + i] >> NBSHIFT], 1);
  __syncthreads();
  lcur[t] = atomicAdd(&gcur[t], hist[t]);
  __syncthreads();
  for (int i = c0 + t; i < cend; i += 256) {
    int dst = ei[e + i];
    int src = ei[i];
    int b = dst >> NBSHIFT;
    int pos = atomicAdd(&lcur[b], 1);
    ebuf[pos] = (unsigned int)src | ((unsigned int)(dst & 255) << 16);
  }
}

// ---------------------------------------------------------------------------
// K5: per-bucket CSR build. One block per coarse bucket: LDS node-histogram,
// LDS scan -> node offsets, LDS cursors -> scatter src into the bucket's
// private ~32KB csr window.
// ---------------------------------------------------------------------------
__global__ __launch_bounds__(256) void csr_build(
    const unsigned int* __restrict__ ebuf, const int* __restrict__ bbase,
    int* __restrict__ offsets, int* __restrict__ csr_src, int n) {
  __shared__ int hist[256];
  __shared__ int sc[256];
  const int b = blockIdx.x;
  const int t = threadIdx.x;
  const int node0 = b << NBSHIFT;
  const int seg0 = bbase[b];
  const int seg1 = bbase[b + 1];

  hist[t] = 0;
  __syncthreads();
  for (int i = seg0 + t; i < seg1; i += 256)
    atomicAdd(&hist[(ebuf[i] >> 16) & 255], 1);
  __syncthreads();
  int v = hist[t];
  sc[t] = v;
  __syncthreads();
#pragma unroll
  for (int s = 1; s < 256; s <<= 1) {
    int add = (t >= s) ? sc[t - s] : 0;
    __syncthreads();
    sc[t] += add;
    __syncthreads();
  }
  int start = seg0 + sc[t] - v;  // exclusive
  int node = node0 + t;
  if (node < n) offsets[node] = start;
  __syncthreads();
  hist[t] = start;  // reuse as cursor
  __syncthreads();
  for (int i = seg0 + t; i < seg1; i += 256) {
    unsigned int u = ebuf[i];
    int pos = atomicAdd(&hist[(u >> 16) & 255], 1);
    csr_src[pos] = (int)(u & 0xFFFFu);
  }
}

// ---------------------------------------------------------------------------
// K6: per-node softmax attention + aggregation.
// One wave per node; lane l owns channel pair (2l, 2l+1). xl is bf16-packed:
// one dword gather per lane per edge (256 B/wave vs 512 fp32 — halves the
// dominant gather traffic). Paired-edge butterfly + SALU addressing (R6).
// ---------------------------------------------------------------------------
__global__ __launch_bounds__(256) void node_agg(
    const unsigned int* __restrict__ xlb, const float* __restrict__ xr,
    const int* __restrict__ offsets, const int* __restrict__ csr_src,
    const float* __restrict__ att, const float* __restrict__ bias,
    float* __restrict__ out, int n) {
  const int wave = threadIdx.x >> 6;
  const int lane = threadIdx.x & 63;
  const int node = blockIdx.x * 4 + wave;
  if (node >= n) return;
  const int ch = lane * 2;

  const float2 xr2 = *(const float2*)(xr + (size_t)node * 128 + ch);
  const float2 a2 = *(const float2*)(att + ch);
  const unsigned int* __restrict__ xlp = xlb + lane;  // + 64*src

  const int start = rfl(offsets[node]);
  const int end = rfl(offsets[node + 1]);

  float s = 0.f;
  float2 acc = make_float2(0.f, 0.f);

  auto unpack = [](unsigned int u) {
    return make_float2(__uint_as_float(u << 16),
                       __uint_as_float(u & 0xFFFF0000u));
  };

  auto partial = [&](float2 v) {
    float t0 = v.x + xr2.x;
    float t1 = v.y + xr2.y;
    t0 = fmaxf(t0, 0.f) + NEG_SLOPE * fminf(t0, 0.f);
    t1 = fmaxf(t1, 0.f) + NEG_SLOPE * fminf(t1, 0.f);
    return fmaf(t0, a2.x, t1 * a2.y);
  };

  auto single_body = [&](float2 v) {
    float p = partial(v);
    p += __shfl_xor(p, 1, 64);
    p += __shfl_xor(p, 2, 64);
    p += __shfl_xor(p, 4, 64);
    p += __shfl_xor(p, 8, 64);
    p += __shfl_xor(p, 16, 64);
    float w = __expf(p);
    s += w;
    acc.x = fmaf(w, v.x, acc.x);
    acc.y = fmaf(w, v.y, acc.y);
  };

  auto pair_body = [&](float2 va, float2 vb) {
    float pa = partial(va);
    float pb = partial(vb);
    pa += __shfl_xor(pa, 1, 64);
    pb += __shfl_xor(pb, 1, 64);
    float z = (lane & 1) ? pb : pa;   // even lanes: a, odd lanes: b
    z += __shfl_xor(z, 2, 64);
    z += __shfl_xor(z, 4, 64);
    z += __shfl_xor(z, 8, 64);
    z += __shfl_xor(z, 16, 64);
    float ew = __expf(z);
    float eo = __shfl_xor(ew, 1, 64);
    float wa = (lane & 1) ? eo : ew;
    float wb = (lane & 1) ? ew : eo;
    s += wa + wb;
    acc.x = fmaf(wa, va.x, acc.x);
    acc.y = fmaf(wa, va.y, acc.y);
    acc.x = fmaf(wb, vb.x, acc.x);
    acc.y = fmaf(wb, vb.y, acc.y);
  };

  const float2 vself = unpack(xlp[(size_t)node * 64]);
  int e = start;
  if ((end - start) & 1) {  // odd in-degree: pair self-loop with first edge
    int s1 = rfl(csr_src[e]);
    ++e;
    pair_body(vself, unpack(xlp[(size_t)s1 * 64]));
  } else {
    single_body(vself);
  }
#pragma unroll 2
  for (; e < end; e += 2) {
    int s0 = rfl(csr_src[e]);
    int s1 = rfl(csr_src[e + 1]);
    float2 va = unpack(xlp[(size_t)s0 * 64]);
    float2 vb = unpack(xlp[(size_t)s1 * 64]);
    pair_body(va, vb);
  }

  const float inv = 1.f / s;
  const float2 b2 = *(const float2*)(bias + ch);
  float2 o = make_float2(fmaf(acc.x, inv, b2.x), fmaf(acc.y, inv, b2.y));
  *(float2*)(out + (size_t)node * 128 + ch) = o;
}

// ---------------------------------------------------------------------------
// K7a: per-channel sum & sumsq partials
// ---------------------------------------------------------------------------
__global__ __launch_bounds__(256) void gn_partial(const float* __restrict__ out,
                                                  float* __restrict__ part,
                                                  int total) {
  float s = 0.f, q = 0.f;
  const int stride = gridDim.x * 256;
  for (int idx = blockIdx.x * 256 + threadIdx.x; idx < total; idx += stride) {
    float v = out[idx];
    s += v;
    q = fmaf(v, v, q);
  }
  __shared__ float sd[256], qd[256];
  sd[threadIdx.x] = s;
  qd[threadIdx.x] = q;
  __syncthreads();
  if (threadIdx.x < 128) {
    part[blockIdx.x * 256 + threadIdx.x] = sd[threadIdx.x] + sd[threadIdx.x + 128];
    part[blockIdx.x * 256 + 128 + threadIdx.x] =
        qd[threadIdx.x] + qd[threadIdx.x + 128];
  }
}

// K7b: combine partials, produce affine params A,B
__global__ void gn_final(const float* __restrict__ part,
                         const float* __restrict__ gw,
                         const float* __restrict__ gb,
                         const float* __restrict__ gms, float* __restrict__ AB,
                         int nblocks, float inv_n) {
  int c = threadIdx.x;  // 128 threads
  float S = 0.f, Q = 0.f;
  for (int b = 0; b < nblocks; ++b) {
    S += part[b * 256 + c];
    Q += part[b * 256 + 128 + c];
  }
  float mean = S * inv_n;
  float msc = mean * gms[c];
  float var = Q * inv_n - 2.f * msc * mean + msc * msc;
  float scale = gw[c] * rsqrtf(var + GN_EPS);
  AB[c] = scale;
  AB[128 + c] = gb[c] - scale * msc;
}

// K7c: in-place normalize, float4-vectorized
__global__ void gn_apply(float* __restrict__ out, const float* __restrict__ AB,
                         int total4) {
  int i = blockIdx.x * blockDim.x + threadIdx.x;
  if (i >= total4) return;
  float4 v = ((float4*)out)[i];
  int c4 = (i & 31) * 4;
  v.x = fmaf(AB[c4 + 0], v.x, AB[128 + c4 + 0]);
  v.y = fmaf(AB[c4 + 1], v.y, AB[128 + c4 + 1]);
  v.z = fmaf(AB[c4 + 2], v.z, AB[128 + c4 + 2]);
  v.w = fmaf(AB[c4 + 3], v.w, AB[128 + c4 + 3]);
  ((float4*)out)[i] = v;
}

// ---------------------------------------------------------------------------
extern "C" void kernel_launch(void* const* d_in, const int* in_sizes, int n_in,
                              void* d_out, int out_size, void* d_ws,
                              size_t ws_size, hipStream_t stream) {
  const float* x = (const float*)d_in[0];
  const int* ei = (const int*)d_in[1];
  const float* Wl = (const float*)d_in[2];
  const float* Wr = (const float*)d_in[3];
  const float* att = (const float*)d_in[4];
  const float* bias = (const float*)d_in[5];
  const float* gw = (const float*)d_in[6];
  const float* gb = (const float*)d_in[7];
  const float* gms = (const float*)d_in[8];
  float* out = (float*)d_out;

  const int n = in_sizes[0] / 128;
  const int e = in_sizes[1] / 2;
  const int nb = (n + 255) >> NBSHIFT;       // coarse buckets (196)
  const int nchunks = (e + CHUNK - 1) / CHUNK;
  const int GN_BLOCKS = 256;

  char* w = (char*)d_ws;
  auto alloc = [&](size_t bytes) {
    char* p = w;
    w += (bytes + 255) & ~(size_t)255;
    return p;
  };
  unsigned int* xlb = (unsigned int*)alloc((size_t)n * 64 * sizeof(int));
  float* xr = (float*)alloc((size_t)n * 128 * sizeof(float));
  int* offsets = (int*)alloc((size_t)(n + 1) * sizeof(int));
  int* csr_src = (int*)alloc((size_t)e * sizeof(int));
  unsigned int* ebuf = (unsigned int*)alloc((size_t)e * sizeof(int));
  int* bhist = (int*)alloc(256 * sizeof(int));
  int* bbase = (int*)alloc((size_t)(nb + 1) * sizeof(int));
  int* gcur = (int*)alloc(256 * sizeof(int));
  float* part = (float*)alloc((size_t)GN_BLOCKS * 256 * sizeof(float));
  float* AB = (float*)alloc(256 * sizeof(float));

  hipMemsetAsync(bhist, 0, 256 * sizeof(int), stream);

  gemm_xw<<<(n + 31) / 32, 256, 0, stream>>>(x, Wl, Wr, xlb, xr, n);
  coarse_hist<<<196, 256, 0, stream>>>(ei, bhist, e);
  bscan<<<1, 256, 0, stream>>>(bhist, bbase, gcur, offsets, nb, n, e);
  partition<<<nchunks, 256, 0, stream>>>(ei, gcur, ebuf, e);
  csr_build<<<nb, 256, 0, stream>>>(ebuf, bbase, offsets, csr_src, n);
  node_agg<<<(n + 3) / 4, 256, 0, stream>>>(xlb, xr, offsets, csr_src, att,
                                            bias, out, n);
  gn_partial<<<GN_BLOCKS, 256, 0, stream>>>(out, part, n * 128);
  gn_final<<<1, 128, 0, stream>>>(part, gw, gb, gms, AB, GN_BLOCKS,
                                  1.0f / (float)n);
  gn_apply<<<(n * 32 + 255) / 256, 256, 0, stream>>>(out, AB, n * 32);
}

// Round 8
// 371.925 us; speedup vs baseline: 1.6755x; 1.0695x over previous
//
#include <hip/hip_runtime.h>
#include <math.h>

// N=50000, E=1600000, F_IN=128, C_OUT=64, HEADS=2, HC=128
#define NEG_SLOPE 0.2f
#define GN_EPS 1e-5f
#define NBSHIFT 8        // 256 nodes per coarse bucket
#define CHUNK 8192       // edges per partition block

__device__ __forceinline__ int rfl(int v) {
  return __builtin_amdgcn_readfirstlane(v);
}

// round-nearest-even f32 -> bf16 (top 16 bits)
__device__ __forceinline__ unsigned int bf16r(float f) {
  unsigned int u = __float_as_uint(f);
  return (u + 0x7fffu + ((u >> 16) & 1u)) >> 16;
}

// ---------------------------------------------------------------------------
// K1: xl(bf16-packed) = x @ W_l, xr(fp32) = x @ W_r.
// Block = 256 thr, tile 32 rows x 256 cols. xl consumer (node_agg) reads
// lane-pair dwords, so pack (ch 2l, ch 2l+1) into one uint.
// ---------------------------------------------------------------------------
__global__ __launch_bounds__(256) void gemm_xw(
    const float* __restrict__ x, const float* __restrict__ Wl,
    const float* __restrict__ Wr, unsigned int* __restrict__ xlb,
    float* __restrict__ xr, int n) {
  __shared__ float xs[32][128];
  const int tid = threadIdx.x;
  const int r0 = blockIdx.x * 32;
  const int rows = min(32, n - r0);

#pragma unroll
  for (int j = 0; j < 4; ++j) {
    int f4 = j * 256 + tid;
    int row = f4 >> 5;
    int c4 = f4 & 31;
    float4 v = make_float4(0.f, 0.f, 0.f, 0.f);
    if (row < rows) v = ((const float4*)(x + (size_t)(r0 + row) * 128))[c4];
    ((float4*)&xs[row][0])[c4] = v;
  }
  __syncthreads();

  const int rg = tid >> 6;
  const int cg = tid & 63;
  const float* __restrict__ W = (cg < 32) ? Wl : Wr;
  const int cb = (cg < 32) ? 4 * cg : 4 * cg - 128;

  float4 acc[8];
#pragma unroll
  for (int r = 0; r < 8; ++r) acc[r] = make_float4(0.f, 0.f, 0.f, 0.f);

#pragma unroll 4
  for (int k4 = 0; k4 < 32; ++k4) {
    float4 xv[8];
#pragma unroll
    for (int r = 0; r < 8; ++r)
      xv[r] = *(const float4*)&xs[rg * 8 + r][k4 * 4];
    float4 w0 = *(const float4*)(W + (size_t)(4 * k4 + 0) * 128 + cb);
    float4 w1 = *(const float4*)(W + (size_t)(4 * k4 + 1) * 128 + cb);
    float4 w2 = *(const float4*)(W + (size_t)(4 * k4 + 2) * 128 + cb);
    float4 w3 = *(const float4*)(W + (size_t)(4 * k4 + 3) * 128 + cb);
#pragma unroll
    for (int r = 0; r < 8; ++r) {
      acc[r].x = fmaf(xv[r].x, w0.x, acc[r].x);
      acc[r].y = fmaf(xv[r].x, w0.y, acc[r].y);
      acc[r].z = fmaf(xv[r].x, w0.z, acc[r].z);
      acc[r].w = fmaf(xv[r].x, w0.w, acc[r].w);
      acc[r].x = fmaf(xv[r].y, w1.x, acc[r].x);
      acc[r].y = fmaf(xv[r].y, w1.y, acc[r].y);
      acc[r].z = fmaf(xv[r].y, w1.z, acc[r].z);
      acc[r].w = fmaf(xv[r].y, w1.w, acc[r].w);
      acc[r].x = fmaf(xv[r].z, w2.x, acc[r].x);
      acc[r].y = fmaf(xv[r].z, w2.y, acc[r].y);
      acc[r].z = fmaf(xv[r].z, w2.z, acc[r].z);
      acc[r].w = fmaf(xv[r].z, w2.w, acc[r].w);
      acc[r].x = fmaf(xv[r].w, w3.x, acc[r].x);
      acc[r].y = fmaf(xv[r].w, w3.y, acc[r].y);
      acc[r].z = fmaf(xv[r].w, w3.z, acc[r].z);
      acc[r].w = fmaf(xv[r].w, w3.w, acc[r].w);
    }
  }

  if (cg < 32) {
#pragma unroll
    for (int r = 0; r < 8; ++r) {
      int row = rg * 8 + r;
      if (row < rows) {
        uint2 p;
        p.x = bf16r(acc[r].x) | (bf16r(acc[r].y) << 16);
        p.y = bf16r(acc[r].z) | (bf16r(acc[r].w) << 16);
        *(uint2*)(xlb + (size_t)(r0 + row) * 64 + (cb >> 1)) = p;
      }
    }
  } else {
#pragma unroll
    for (int r = 0; r < 8; ++r) {
      int row = rg * 8 + r;
      if (row < rows)
        *(float4*)(xr + (size_t)(r0 + row) * 128 + cb) = acc[r];
    }
  }
}

// ---------------------------------------------------------------------------
// K2: coarse histogram (196 buckets of 256 nodes) via LDS, tiny global merge
// ---------------------------------------------------------------------------
__global__ __launch_bounds__(256) void coarse_hist(const int* __restrict__ ei,
                                                   int* __restrict__ bhist,
                                                   int e) {
  __shared__ int hist[256];
  hist[threadIdx.x] = 0;
  __syncthreads();
  const int stride = gridDim.x * 256;
  for (int i = blockIdx.x * 256 + threadIdx.x; i < e; i += stride)
    atomicAdd(&hist[ei[e + i] >> NBSHIFT], 1);
  __syncthreads();
  int v = hist[threadIdx.x];
  if (v > 0) atomicAdd(&bhist[threadIdx.x], v);
}

// ---------------------------------------------------------------------------
// K3: exclusive scan of bucket counts -> bbase[nb+1], init gcur, sentinel
// ---------------------------------------------------------------------------
__global__ __launch_bounds__(256) void bscan(const int* __restrict__ bhist,
                                             int* __restrict__ bbase,
                                             int* __restrict__ gcur,
                                             int* __restrict__ offsets, int nb,
                                             int n, int e) {
  __shared__ int sd[256];
  int t = threadIdx.x;
  int v = (t < nb) ? bhist[t] : 0;
  sd[t] = v;
  __syncthreads();
#pragma unroll
  for (int s = 1; s < 256; s <<= 1) {
    int add = (t >= s) ? sd[t - s] : 0;
    __syncthreads();
    sd[t] += add;
    __syncthreads();
  }
  int excl = sd[t] - v;
  if (t < nb) {
    bbase[t] = excl;
    gcur[t] = excl;
  } else {
    gcur[t] = 0;
  }
  if (t == 0) {
    bbase[nb] = e;
    offsets[n] = e;
  }
}

// ---------------------------------------------------------------------------
// K4: partition. Each block owns CHUNK edges: LDS histogram over buckets,
// claims ONE contiguous run per bucket (single atomicAdd), then writes its
// edges into its own runs (single writer per L2 line -> full-line
// writebacks). Packed entry: src (16b) | local_dst (8b) << 16.
// ---------------------------------------------------------------------------
__global__ __launch_bounds__(256) void partition(const int* __restrict__ ei,
                                                 int* __restrict__ gcur,
                                                 unsigned int* __restrict__ ebuf,
                                                 int e) {
  __shared__ int hist[256];
  __shared__ int lcur[256];
  const int t = threadIdx.x;
  const int c0 = blockIdx.x * CHUNK;
  const int cend = min(c0 + CHUNK, e);
  hist[t] = 0;
  __syncthreads();
  for (int i = c0 + t; i < cend; i += 256)
    atomicAdd(&hist[ei[e + i] >> NBSHIFT], 1);
  __syncthreads();
  lcur[t] = atomicAdd(&gcur[t], hist[t]);
  __syncthreads();
  for (int i = c0 + t; i < cend; i += 256) {
    int dst = ei[e + i];
    int src = ei[i];
    int b = dst >> NBSHIFT;
    int pos = atomicAdd(&lcur[b], 1);
    ebuf[pos] = (unsigned int)src | ((unsigned int)(dst & 255) << 16);
  }
}

// ---------------------------------------------------------------------------
// K5: per-bucket CSR build. One block per coarse bucket: LDS node-histogram,
// LDS scan -> node offsets, LDS cursors -> scatter src into the bucket's
// private ~32KB csr window.
// ---------------------------------------------------------------------------
__global__ __launch_bounds__(256) void csr_build(
    const unsigned int* __restrict__ ebuf, const int* __restrict__ bbase,
    int* __restrict__ offsets, int* __restrict__ csr_src, int n) {
  __shared__ int hist[256];
  __shared__ int sc[256];
  const int b = blockIdx.x;
  const int t = threadIdx.x;
  const int node0 = b << NBSHIFT;
  const int seg0 = bbase[b];
  const int seg1 = bbase[b + 1];

  hist[t] = 0;
  __syncthreads();
  for (int i = seg0 + t; i < seg1; i += 256)
    atomicAdd(&hist[(ebuf[i] >> 16) & 255], 1);
  __syncthreads();
  int v = hist[t];
  sc[t] = v;
  __syncthreads();
#pragma unroll
  for (int s = 1; s < 256; s <<= 1) {
    int add = (t >= s) ? sc[t - s] : 0;
    __syncthreads();
    sc[t] += add;
    __syncthreads();
  }
  int start = seg0 + sc[t] - v;  // exclusive
  int node = node0 + t;
  if (node < n) offsets[node] = start;
  __syncthreads();
  hist[t] = start;  // reuse as cursor
  __syncthreads();
  for (int i = seg0 + t; i < seg1; i += 256) {
    unsigned int u = ebuf[i];
    int pos = atomicAdd(&hist[(u >> 16) & 255], 1);
    csr_src[pos] = (int)(u & 0xFFFFu);
  }
}

// ---------------------------------------------------------------------------
// K6: per-node softmax attention + aggregation.
// One wave per node; lane l owns channel pair (2l, 2l+1). xl bf16-packed
// (one dword gather/lane/edge). R8: batch 64 edge indices in ONE vector
// load (readlane broadcasts, SALU addresses) + quad body issuing 4 gathers
// before any butterfly, unroll 2 -> up to 8 gathers in flight (R7 had 2,
// stalling on a csr_src->gather dependent chain every pair).
// ---------------------------------------------------------------------------
__global__ __launch_bounds__(256) void node_agg(
    const unsigned int* __restrict__ xlb, const float* __restrict__ xr,
    const int* __restrict__ offsets, const int* __restrict__ csr_src,
    const float* __restrict__ att, const float* __restrict__ bias,
    float* __restrict__ out, int n) {
  const int wave = threadIdx.x >> 6;
  const int lane = threadIdx.x & 63;
  const int node = blockIdx.x * 4 + wave;
  if (node >= n) return;
  const int ch = lane * 2;

  const float2 xr2 = *(const float2*)(xr + (size_t)node * 128 + ch);
  const float2 a2 = *(const float2*)(att + ch);
  const unsigned int* __restrict__ xlp = xlb + lane;  // + 64*src

  const int start = rfl(offsets[node]);
  const int end = rfl(offsets[node + 1]);
  const int deg = end - start;

  float s = 0.f;
  float2 acc = make_float2(0.f, 0.f);

  auto unpack = [](unsigned int u) {
    return make_float2(__uint_as_float(u << 16),
                       __uint_as_float(u & 0xFFFF0000u));
  };

  auto partial = [&](float2 v) {
    float t0 = v.x + xr2.x;
    float t1 = v.y + xr2.y;
    t0 = fmaxf(t0, 0.f) + NEG_SLOPE * fminf(t0, 0.f);
    t1 = fmaxf(t1, 0.f) + NEG_SLOPE * fminf(t1, 0.f);
    return fmaf(t0, a2.x, t1 * a2.y);
  };

  auto single_body = [&](float2 v) {
    float p = partial(v);
    p += __shfl_xor(p, 1, 64);
    p += __shfl_xor(p, 2, 64);
    p += __shfl_xor(p, 4, 64);
    p += __shfl_xor(p, 8, 64);
    p += __shfl_xor(p, 16, 64);
    float w = __expf(p);
    s += w;
    acc.x = fmaf(w, v.x, acc.x);
    acc.y = fmaf(w, v.y, acc.y);
  };

  auto pair_body = [&](float2 va, float2 vb) {
    float pa = partial(va);
    float pb = partial(vb);
    pa += __shfl_xor(pa, 1, 64);
    pb += __shfl_xor(pb, 1, 64);
    float z = (lane & 1) ? pb : pa;   // even lanes: a, odd lanes: b
    z += __shfl_xor(z, 2, 64);
    z += __shfl_xor(z, 4, 64);
    z += __shfl_xor(z, 8, 64);
    z += __shfl_xor(z, 16, 64);
    float ew = __expf(z);
    float eo = __shfl_xor(ew, 1, 64);
    float wa = (lane & 1) ? eo : ew;
    float wb = (lane & 1) ? ew : eo;
    s += wa + wb;
    acc.x = fmaf(wa, va.x, acc.x);
    acc.y = fmaf(wa, va.y, acc.y);
    acc.x = fmaf(wb, vb.x, acc.x);
    acc.y = fmaf(wb, vb.y, acc.y);
  };

  // self-loop
  single_body(unpack(xlp[(size_t)node * 64]));

  for (int b0 = 0; b0 < deg; b0 += 64) {
    const int m = min(64, deg - b0);
    // one vector load covers up to 64 edge indices (clamped at tail)
    const int idxv = csr_src[start + b0 + min(lane, m - 1)];
    int j = 0;
#pragma unroll 2
    for (; j + 3 < m; j += 4) {
      int s0 = __builtin_amdgcn_readlane(idxv, j);
      int s1 = __builtin_amdgcn_readlane(idxv, j + 1);
      int s2 = __builtin_amdgcn_readlane(idxv, j + 2);
      int s3 = __builtin_amdgcn_readlane(idxv, j + 3);
      unsigned int u0 = xlp[(size_t)s0 * 64];
      unsigned int u1 = xlp[(size_t)s1 * 64];
      unsigned int u2 = xlp[(size_t)s2 * 64];
      unsigned int u3 = xlp[(size_t)s3 * 64];
      pair_body(unpack(u0), unpack(u1));
      pair_body(unpack(u2), unpack(u3));
    }
    if (j + 1 < m) {
      int s0 = __builtin_amdgcn_readlane(idxv, j);
      int s1 = __builtin_amdgcn_readlane(idxv, j + 1);
      pair_body(unpack(xlp[(size_t)s0 * 64]), unpack(xlp[(size_t)s1 * 64]));
      j += 2;
    }
    if (j < m) {
      int s0 = __builtin_amdgcn_readlane(idxv, j);
      single_body(unpack(xlp[(size_t)s0 * 64]));
    }
  }

  const float inv = 1.f / s;
  const float2 b2 = *(const float2*)(bias + ch);
  float2 o = make_float2(fmaf(acc.x, inv, b2.x), fmaf(acc.y, inv, b2.y));
  *(float2*)(out + (size_t)node * 128 + ch) = o;
}

// ---------------------------------------------------------------------------
// K7a: per-channel sum & sumsq partials
// ---------------------------------------------------------------------------
__global__ __launch_bounds__(256) void gn_partial(const float* __restrict__ out,
                                                  float* __restrict__ part,
                                                  int total) {
  float s = 0.f, q = 0.f;
  const int stride = gridDim.x * 256;
  for (int idx = blockIdx.x * 256 + threadIdx.x; idx < total; idx += stride) {
    float v = out[idx];
    s += v;
    q = fmaf(v, v, q);
  }
  __shared__ float sd[256], qd[256];
  sd[threadIdx.x] = s;
  qd[threadIdx.x] = q;
  __syncthreads();
  if (threadIdx.x < 128) {
    part[blockIdx.x * 256 + threadIdx.x] = sd[threadIdx.x] + sd[threadIdx.x + 128];
    part[blockIdx.x * 256 + 128 + threadIdx.x] =
        qd[threadIdx.x] + qd[threadIdx.x + 128];
  }
}

// K7b: combine partials, produce affine params A,B
__global__ void gn_final(const float* __restrict__ part,
                         const float* __restrict__ gw,
                         const float* __restrict__ gb,
                         const float* __restrict__ gms, float* __restrict__ AB,
                         int nblocks, float inv_n) {
  int c = threadIdx.x;  // 128 threads
  float S = 0.f, Q = 0.f;
  for (int b = 0; b < nblocks; ++b) {
    S += part[b * 256 + c];
    Q += part[b * 256 + 128 + c];
  }
  float mean = S * inv_n;
  float msc = mean * gms[c];
  float var = Q * inv_n - 2.f * msc * mean + msc * msc;
  float scale = gw[c] * rsqrtf(var + GN_EPS);
  AB[c] = scale;
  AB[128 + c] = gb[c] - scale * msc;
}

// K7c: in-place normalize, float4-vectorized
__global__ void gn_apply(float* __restrict__ out, const float* __restrict__ AB,
                         int total4) {
  int i = blockIdx.x * blockDim.x + threadIdx.x;
  if (i >= total4) return;
  float4 v = ((float4*)out)[i];
  int c4 = (i & 31) * 4;
  v.x = fmaf(AB[c4 + 0], v.x, AB[128 + c4 + 0]);
  v.y = fmaf(AB[c4 + 1], v.y, AB[128 + c4 + 1]);
  v.z = fmaf(AB[c4 + 2], v.z, AB[128 + c4 + 2]);
  v.w = fmaf(AB[c4 + 3], v.w, AB[128 + c4 + 3]);
  ((float4*)out)[i] = v;
}

// ---------------------------------------------------------------------------
extern "C" void kernel_launch(void* const* d_in, const int* in_sizes, int n_in,
                              void* d_out, int out_size, void* d_ws,
                              size_t ws_size, hipStream_t stream) {
  const float* x = (const float*)d_in[0];
  const int* ei = (const int*)d_in[1];
  const float* Wl = (const float*)d_in[2];
  const float* Wr = (const float*)d_in[3];
  const float* att = (const float*)d_in[4];
  const float* bias = (const float*)d_in[5];
  const float* gw = (const float*)d_in[6];
  const float* gb = (const float*)d_in[7];
  const float* gms = (const float*)d_in[8];
  float* out = (float*)d_out;

  const int n = in_sizes[0] / 128;
  const int e = in_sizes[1] / 2;
  const int nb = (n + 255) >> NBSHIFT;       // coarse buckets (196)
  const int nchunks = (e + CHUNK - 1) / CHUNK;
  const int GN_BLOCKS = 256;

  char* w = (char*)d_ws;
  auto alloc = [&](size_t bytes) {
    char* p = w;
    w += (bytes + 255) & ~(size_t)255;
    return p;
  };
  unsigned int* xlb = (unsigned int*)alloc((size_t)n * 64 * sizeof(int));
  float* xr = (float*)alloc((size_t)n * 128 * sizeof(float));
  int* offsets = (int*)alloc((size_t)(n + 1) * sizeof(int));
  int* csr_src = (int*)alloc((size_t)e * sizeof(int));
  unsigned int* ebuf = (unsigned int*)alloc((size_t)e * sizeof(int));
  int* bhist = (int*)alloc(256 * sizeof(int));
  int* bbase = (int*)alloc((size_t)(nb + 1) * sizeof(int));
  int* gcur = (int*)alloc(256 * sizeof(int));
  float* part = (float*)alloc((size_t)GN_BLOCKS * 256 * sizeof(float));
  float* AB = (float*)alloc(256 * sizeof(float));

  hipMemsetAsync(bhist, 0, 256 * sizeof(int), stream);

  gemm_xw<<<(n + 31) / 32, 256, 0, stream>>>(x, Wl, Wr, xlb, xr, n);
  coarse_hist<<<196, 256, 0, stream>>>(ei, bhist, e);
  bscan<<<1, 256, 0, stream>>>(bhist, bbase, gcur, offsets, nb, n, e);
  partition<<<nchunks, 256, 0, stream>>>(ei, gcur, ebuf, e);
  csr_build<<<nb, 256, 0, stream>>>(ebuf, bbase, offsets, csr_src, n);
  node_agg<<<(n + 3) / 4, 256, 0, stream>>>(xlb, xr, offsets, csr_src, att,
                                            bias, out, n);
  gn_partial<<<GN_BLOCKS, 256, 0, stream>>>(out, part, n * 128);
  gn_final<<<1, 128, 0, stream>>>(part, gw, gb, gms, AB, GN_BLOCKS,
                                  1.0f / (float)n);
  gn_apply<<<(n * 32 + 255) / 256, 256, 0, stream>>>(out, AB, n * 32);
}